// Round 3
// baseline (389.006 us; speedup 1.0000x reference)
//
#include <hip/hip_runtime.h>
#include <hip/hip_bf16.h>

#define D 1024
#define H 16
#define DH 64
#define KN 32768
#define EPS 1e-5f
#define NBLK 256   // g_attn blocks; each handles 128 neighbor rows

__device__ __forceinline__ float wave_sum(float v){
  #pragma unroll
  for (int off = 32; off; off >>= 1) v += __shfl_xor(v, off, 64);
  return v;
}

// K1: q[j] = query . wq_row(j) + bq[j]   (one wave per output)
__global__ void g_qproj(const float* __restrict__ query, const float* __restrict__ ipw,
                        const float* __restrict__ ipb, float* __restrict__ q){
  int j = blockIdx.x, l = threadIdx.x;
  const float4* qv = (const float4*)(query + l*16);
  const float4* wv = (const float4*)(ipw + (size_t)j*D + l*16);
  float acc = 0.f;
  #pragma unroll
  for (int t = 0; t < 4; t++){
    float4 a = qv[t], b = wv[t];
    acc += a.x*b.x + a.y*b.y + a.z*b.z + a.w*b.w;
  }
  acc = wave_sum(acc);
  if (l == 0) q[j] = acc + ipb[j];
}

// K2: qk[h][col] = sum_j q[64h+j]*wk[64h+j][col]; block 64: sb[h] = q_h . bk_h
__global__ __launch_bounds__(256) void g_qk(const float* __restrict__ ipw, const float* __restrict__ ipb,
                                            const float* __restrict__ q, float* __restrict__ qk,
                                            float* __restrict__ sb){
  int b = blockIdx.x, t = threadIdx.x;
  if (b == 64){
    if (t < H){
      float s = 0.f;
      for (int j = 0; j < DH; j++) s += q[t*DH + j] * ipb[D + t*DH + j];
      sb[t] = s;
    }
    return;
  }
  int h = b >> 2, cc = b & 3;
  __shared__ float qh[DH];
  if (t < DH) qh[t] = q[h*DH + t];
  __syncthreads();
  int col = cc*256 + t;
  const float* wbase = ipw + (size_t)(D + h*DH)*D + col;
  float acc = 0.f;
  #pragma unroll 8
  for (int j = 0; j < DH; j++) acc += qh[j] * wbase[(size_t)j*D];
  qk[h*D + col] = acc;
}

// K3: fused scoreless attention. Block b: k in [b*128, b*128+128).
// Thread (h = t>>4, ci = t&15) owns cols ci*64..ci*64+63 of head h.
// Per row: s = qk_h . n_k (16-lane xor reduce), p = exp((s+sb_h)/8),
// acc += p*n_k[cols]. Block partials -> part[b], lpart[b] (no atomics).
// LDS: double-buffered 8-row tile, XOR-swizzled (read quads spread; 4 h-lanes broadcast).
__global__ __launch_bounds__(256, 1) void g_attn(const float* __restrict__ nbr, const float* __restrict__ qk,
                                                 const float* __restrict__ sb, float* __restrict__ lpart,
                                                 float* __restrict__ part){
  __shared__ __align__(16) float tile[2][8*D];   // 64 KiB
  int t = threadIdx.x;
  int h = t >> 4, ci = t & 15;
  float sbh = sb[h];

  float qkv[64];
  {
    const float4* qp = (const float4*)(qk + h*D + ci*64);
    #pragma unroll
    for (int i = 0; i < 16; i++){
      float4 f = qp[i];
      qkv[4*i]=f.x; qkv[4*i+1]=f.y; qkv[4*i+2]=f.z; qkv[4*i+3]=f.w;
    }
  }
  float acc[64];
  #pragma unroll
  for (int i = 0; i < 64; i++) acc[i] = 0.f;
  float lsum = 0.f;

  const int k0 = blockIdx.x * 128;
  float4 st[8];

  // preload tile 0
  {
    const float4* g = (const float4*)(nbr + (size_t)k0*D);
    #pragma unroll
    for (int i = 0; i < 8; i++) st[i] = g[i*256 + t];
    #pragma unroll
    for (int i = 0; i < 8; i++){
      int f = i*256 + t, r = f >> 8, fr = f & 255;
      int cw = fr >> 4, cl = fr & 15;
      ((float4*)tile[0])[r*256 + cw*16 + (cl ^ cw)] = st[i];
    }
  }
  __syncthreads();

  #pragma unroll 1
  for (int kk = 0; kk < 128; kk += 8){
    int cur = (kk >> 3) & 1;
    bool has_next = (kk + 8) < 128;
    if (has_next){
      const float4* g = (const float4*)(nbr + (size_t)(k0 + kk + 8)*D);
      #pragma unroll
      for (int i = 0; i < 8; i++) st[i] = g[i*256 + t];   // in flight during compute
    }
    #pragma unroll 1
    for (int r = 0; r < 8; r++){
      const float4* row4 = (const float4*)(tile[cur] + r*D) + ci*16;
      float xf[64];
      float s = 0.f;
      #pragma unroll
      for (int c = 0; c < 16; c++){
        float4 a = row4[c ^ ci];
        xf[4*c]=a.x; xf[4*c+1]=a.y; xf[4*c+2]=a.z; xf[4*c+3]=a.w;
        s += a.x*qkv[4*c] + a.y*qkv[4*c+1] + a.z*qkv[4*c+2] + a.w*qkv[4*c+3];
      }
      #pragma unroll
      for (int off = 1; off < 16; off <<= 1) s += __shfl_xor(s, off, 64);
      float p = __expf((s + sbh)*0.125f);
      lsum += p;
      #pragma unroll
      for (int i = 0; i < 64; i++) acc[i] += p*xf[i];
    }
    if (has_next){
      #pragma unroll
      for (int i = 0; i < 8; i++){
        int f = i*256 + t, r = f >> 8, fr = f & 255;
        int cw = fr >> 4, cl = fr & 15;
        ((float4*)tile[cur ^ 1])[r*256 + cw*16 + (cl ^ cw)] = st[i];
      }
    }
    __syncthreads();
  }

  if (ci == 0) lpart[blockIdx.x*H + h] = lsum;
  float4* o = (float4*)(part + (size_t)blockIdx.x*(H*D) + h*D + ci*64);
  #pragma unroll
  for (int i = 0; i < 16; i++)
    o[i] = make_float4(acc[4*i], acc[4*i+1], acc[4*i+2], acc[4*i+3]);
}

// K4: nb[o] = sum_b part[b][o]; block 64: lh[h] = sum_b lpart[b][h]
__global__ __launch_bounds__(256) void g_red(const float* __restrict__ part, const float* __restrict__ lpart,
                                             float* __restrict__ nb, float* __restrict__ lh){
  int b = blockIdx.x, t = threadIdx.x;
  if (b == 64){
    if (t < H){
      float s = 0.f;
      for (int c = 0; c < NBLK; c++) s += lpart[c*H + t];
      lh[t] = s;
    }
    return;
  }
  int o = b*256 + t;
  float s = 0.f;
  #pragma unroll 8
  for (int c = 0; c < NBLK; c++) s += part[(size_t)c*(H*D) + o];
  nb[o] = s;
}

// K5: ctx[j] = wv_row(j) . (nb[h]/lh[h]) + bv[j]
__global__ void g_ctx(const float* __restrict__ ipw, const float* __restrict__ ipb,
                      const float* __restrict__ nb, const float* __restrict__ lh,
                      float* __restrict__ ctx){
  int j = blockIdx.x, l = threadIdx.x, h = j >> 6;
  const float4* wv = (const float4*)(ipw + (size_t)(2*D + j)*D + l*16);
  const float4* nv = (const float4*)(nb + h*D + l*16);
  float acc = 0.f;
  #pragma unroll
  for (int t = 0; t < 4; t++){
    float4 b = wv[t], n = nv[t];
    acc += b.x*n.x + b.y*n.y + b.z*n.z + b.w*n.w;
  }
  acc = wave_sum(acc);
  if (l == 0) ctx[j] = acc/lh[h] + ipb[2*D + j];
}

// K6: xb[j] = query[j] + out_proj_w_row(j) . ctx + out_proj_b[j]
__global__ void g_attnout(const float* __restrict__ opw, const float* __restrict__ opb,
                          const float* __restrict__ query, const float* __restrict__ ctx,
                          float* __restrict__ xb){
  int j = blockIdx.x, l = threadIdx.x;
  const float4* wv = (const float4*)(opw + (size_t)j*D + l*16);
  const float4* cv = (const float4*)(ctx + l*16);
  float acc = 0.f;
  #pragma unroll
  for (int t = 0; t < 4; t++){
    float4 b = wv[t], c = cv[t];
    acc += b.x*c.x + b.y*c.y + b.z*c.z + b.w*c.w;
  }
  acc = wave_sum(acc);
  if (l == 0) xb[j] = query[j] + acc + opb[j];
}

// K7: in-place LayerNorm on xb (1024 elems, one block)
__global__ __launch_bounds__(1024) void g_ln1(float* __restrict__ xb,
                                              const float* __restrict__ g, const float* __restrict__ be){
  int t = threadIdx.x;
  __shared__ float red[16];
  __shared__ float bc;
  float v = xb[t];
  float s = wave_sum(v);
  if ((t & 63) == 0) red[t >> 6] = s;
  __syncthreads();
  if (t == 0){ float a = 0.f; for (int i = 0; i < 16; i++) a += red[i]; bc = a*(1.0f/D); }
  __syncthreads();
  float m = bc;
  float d = v - m;
  float s2 = wave_sum(d*d);
  if ((t & 63) == 0) red[t >> 6] = s2;
  __syncthreads();
  if (t == 0){ float a = 0.f; for (int i = 0; i < 16; i++) a += red[i]; bc = a*(1.0f/D); }
  __syncthreads();
  float rs = rsqrtf(bc + EPS);
  xb[t] = d*rs*g[t] + be[t];
}

// K8: h1[j] = gelu(w1_row(j) . xb + b1[j])   exact gelu
__global__ void g_ffn1(const float* __restrict__ w1, const float* __restrict__ b1,
                       const float* __restrict__ x, float* __restrict__ h1){
  int j = blockIdx.x, l = threadIdx.x;
  const float4* wv = (const float4*)(w1 + (size_t)j*D + l*16);
  const float4* xv = (const float4*)(x + l*16);
  float acc = 0.f;
  #pragma unroll
  for (int t = 0; t < 4; t++){
    float4 b = wv[t], xx = xv[t];
    acc += b.x*xx.x + b.y*xx.y + b.z*xx.z + b.w*xx.w;
  }
  acc = wave_sum(acc);
  if (l == 0){
    float z = acc + b1[j];
    h1[j] = 0.5f*z*(1.0f + erff(z*0.70710678118654752f));
  }
}

// K9: y[j] = w2_row(j) . h1 + b2[j]   (row length 4096)
__global__ void g_ffn2(const float* __restrict__ w2, const float* __restrict__ b2v,
                       const float* __restrict__ h1, float* __restrict__ y){
  int j = blockIdx.x, l = threadIdx.x;
  const float4* wv = (const float4*)(w2 + (size_t)j*4096 + l*64);
  const float4* hv = (const float4*)(h1 + l*64);
  float acc = 0.f;
  #pragma unroll
  for (int t = 0; t < 16; t++){
    float4 b = wv[t], hh = hv[t];
    acc += b.x*hh.x + b.y*hh.y + b.z*hh.z + b.w*hh.w;
  }
  acc = wave_sum(acc);
  if (l == 0) y[j] = acc + b2v[j];
}

// K10: out = LN(xb + y)*g2 + be2   (fp32 out)
__global__ __launch_bounds__(1024) void g_ln2(const float* __restrict__ xb, const float* __restrict__ y,
                                              const float* __restrict__ g, const float* __restrict__ be,
                                              float* __restrict__ out){
  int t = threadIdx.x;
  __shared__ float red[16];
  __shared__ float bc;
  float v = xb[t] + y[t];
  float s = wave_sum(v);
  if ((t & 63) == 0) red[t >> 6] = s;
  __syncthreads();
  if (t == 0){ float a = 0.f; for (int i = 0; i < 16; i++) a += red[i]; bc = a*(1.0f/D); }
  __syncthreads();
  float m = bc;
  float d = v - m;
  float s2 = wave_sum(d*d);
  if ((t & 63) == 0) red[t >> 6] = s2;
  __syncthreads();
  if (t == 0){ float a = 0.f; for (int i = 0; i < 16; i++) a += red[i]; bc = a*(1.0f/D); }
  __syncthreads();
  float rs = rsqrtf(bc + EPS);
  out[t] = d*rs*g[t] + be[t];
}

extern "C" void kernel_launch(void* const* d_in, const int* in_sizes, int n_in,
                              void* d_out, int out_size, void* d_ws, size_t ws_size,
                              hipStream_t stream) {
  const float* query = (const float*)d_in[0];
  const float* nbr   = (const float*)d_in[1];
  const float* ipw   = (const float*)d_in[2];
  const float* ipb   = (const float*)d_in[3];
  const float* opw   = (const float*)d_in[4];
  const float* opb   = (const float*)d_in[5];
  const float* w1    = (const float*)d_in[6];
  const float* b1    = (const float*)d_in[7];
  const float* w2    = (const float*)d_in[8];
  const float* b2v   = (const float*)d_in[9];
  const float* g1    = (const float*)d_in[10];
  const float* be1   = (const float*)d_in[11];
  const float* g2    = (const float*)d_in[12];
  const float* be2   = (const float*)d_in[13];

  // workspace layout (floats): ~17 MB total
  float* ws    = (float*)d_ws;
  float* q     = ws;               // 1024
  float* qk    = q + D;            // 16384
  float* sb    = qk + H*D;         // 16
  float* lh    = sb + 16;          // 16
  float* ctx   = lh + 16;          // 1024
  float* xb    = ctx + D;          // 1024
  float* h1    = xb + D;           // 4096
  float* y     = h1 + 4*D;         // 1024
  float* nb    = y + D;            // 16384
  float* lpart = nb + H*D;         // NBLK*16 = 4096
  float* part  = lpart + NBLK*H;   // NBLK*16384 = 4194304 (16 MB)

  g_qproj  <<<1024, 64, 0, stream>>>(query, ipw, ipb, q);
  g_qk     <<<65, 256, 0, stream>>>(ipw, ipb, q, qk, sb);
  g_attn   <<<NBLK, 256, 0, stream>>>(nbr, qk, sb, lpart, part);
  g_red    <<<65, 256, 0, stream>>>(part, lpart, nb, lh);
  g_ctx    <<<1024, 64, 0, stream>>>(ipw, ipb, nb, lh, ctx);
  g_attnout<<<1024, 64, 0, stream>>>(opw, opb, query, ctx, xb);
  g_ln1    <<<1, 1024, 0, stream>>>(xb, g1, be1);
  g_ffn1   <<<4096, 64, 0, stream>>>(w1, b1, xb, h1);
  g_ffn2   <<<1024, 64, 0, stream>>>(w2, b2v, h1, y);
  g_ln2    <<<1, 1024, 0, stream>>>(xb, y, g2, be2, (float*)d_out);
}